// Round 13
// baseline (180.709 us; speedup 1.0000x reference)
//
#include <hip/hip_runtime.h>
#include <hip/hip_bf16.h>

// LFQ argmax, round 27: MFMA shape 32x32x16 (the r23 pre-committed pivot).
// r15-r26: twelve structural variants (sync, TLP, stagger, L2 affinity,
// LDS removal, SGB interleave) ALL pinned at ~100us. Every scheduling
// hypothesis dead. The one invariant never varied: the MFMA stream itself
// (4.19M x 16x16x32). The unexplained ~55% must scale with per-MFMA
// overhead (operand-read/issue costs the register-reuse m06 ubench hides).
// Change: 32x32x16 -> HALF the MFMA instructions (2.1M), +20% pipe ceiling
// (2495 vs 2075 TF, m119). Per wave: 64 tokens = 2 row-tiles x 32; 64
// col-tiles x (2rt x 8 K-steps) MFMA; B traffic/wave unchanged (512KB).
// Screen unchanged in op count; f32x16 acc; pk packs col-tile (ct<=63).
// C/D layout row=(reg&3)+8*(reg>>2)+4*(lane>>5) [m74/m101-verified];
// A/B lane maps are the 32-lane analog of the refcheck'd 16x16 maps --
// absmax=0 is the layout canary. Dropped proven-null SGB/setprio/sleep.
// Canaries: FETCH ~35MB (spill!), WRITE ~2MB, VGPR <= 256.
// Numerics: 1-term bf16 screen, 7-bit ct-pack top-2 per split, MARGIN 0.4
// exact rescore (validated r15-r26).
#define NT 16384
#define ND 128
#define NC 16384
#define NSPLIT 8
#define MARGIN 0.4f       // >= 3x worst pairwise 1-term bf16 comparison error

typedef __bf16 bf16x8 __attribute__((ext_vector_type(8)));
typedef unsigned short u16x8 __attribute__((ext_vector_type(8)));
typedef float f32x16 __attribute__((ext_vector_type(16)));

#define MF32 __builtin_amdgcn_mfma_f32_32x32x16_bf16

static __device__ __forceinline__ unsigned short f2bf(float f) {
    unsigned u = __float_as_uint(f);
    return (unsigned short)((u + 0x7FFFu + ((u >> 16) & 1u)) >> 16);
}
static __device__ __forceinline__ bf16x8 u2b(u16x8 u) {
    return __builtin_bit_cast(bf16x8, u);
}

// ---- codebook fp32 -> bf16 hi, fragment-coalesced image for 32x32x16 ----
// Fragment (split, ct, m) = 1KB: [half][col][8 bf16]; lane l=(half<<5)|col
// reads byte l*16. Element (code c, dim d): split=c>>11, ct=(c&2047)>>5,
// col=c&31, m=d>>4, half=(d>>3)&1, e=d&7.
// u16 idx = split*262144 + ct*4096 + m*512 + half*256 + col*8 + e.
__global__ __launch_bounds__(256) void lfq_convert_cb(
    const float4* __restrict__ cb4, unsigned short* __restrict__ cbs)
{
    const unsigned i = blockIdx.x * 256 + threadIdx.x;   // 0..262143
    const unsigned c  = i >> 4;          // code 0..16383
    const unsigned k8 = i & 15u;         // dim chunk (d0 = k8*8)
    const float4 v0 = cb4[i * 2];
    const float4 v1 = cb4[i * 2 + 1];
    const unsigned split = c >> 11;
    const unsigned cl    = c & 2047u;
    const unsigned ct    = cl >> 5;
    const unsigned col   = cl & 31u;
    const unsigned m     = k8 >> 1;
    const unsigned half  = k8 & 1u;
    const unsigned idx = split * 262144u + ct * 4096u + m * 512u +
                         half * 256u + col * 8u;
    u16x8 h;
    h[0] = f2bf(v0.x); h[1] = f2bf(v0.y); h[2] = f2bf(v0.z); h[3] = f2bf(v0.w);
    h[4] = f2bf(v1.x); h[5] = f2bf(v1.y); h[6] = f2bf(v1.z); h[7] = f2bf(v1.w);
    *(u16x8*)(cbs + idx) = h;
}

// exact fp32 dot, register-preloaded x (fallback kernel)
static __device__ __forceinline__ float exact_dot(
    const float4* __restrict__ xr4, const float* __restrict__ cf, int cidx)
{
    const float4* cr = (const float4*)(cf + (size_t)cidx * ND);
    float a0 = 0.f, a1 = 0.f, a2 = 0.f, a3 = 0.f;
#pragma unroll
    for (int i = 0; i < 32; i += 4) {
        float4 x0 = xr4[i+0], x1 = xr4[i+1], x2 = xr4[i+2], x3 = xr4[i+3];
        float4 c0 = cr[i+0],  c1 = cr[i+1],  c2 = cr[i+2],  c3 = cr[i+3];
        a0 += x0.x*c0.x + x0.y*c0.y + x0.z*c0.z + x0.w*c0.w;
        a1 += x1.x*c1.x + x1.y*c1.y + x1.z*c1.z + x1.w*c1.w;
        a2 += x2.x*c2.x + x2.y*c2.y + x2.z*c2.z + x2.w*c2.w;
        a3 += x3.x*c3.x + x3.y*c3.y + x3.z*c3.z + x3.w*c3.w;
    }
    return (a0 + a1) + (a2 + a3);
}

// exact fp32 dot, both operands from global (combine kernel)
static __device__ __forceinline__ float exact_dot_g(
    const float* __restrict__ xf, const float* __restrict__ cf,
    int token, int cidx)
{
    const float4* xr = (const float4*)(xf + (size_t)token * ND);
    const float4* cr = (const float4*)(cf + (size_t)cidx * ND);
    float a0 = 0.f, a1 = 0.f, a2 = 0.f, a3 = 0.f;
#pragma unroll
    for (int i = 0; i < 32; i += 4) {
        float4 x0 = xr[i+0], x1 = xr[i+1], x2 = xr[i+2], x3 = xr[i+3];
        float4 c0 = cr[i+0], c1 = cr[i+1], c2 = cr[i+2], c3 = cr[i+3];
        a0 += x0.x*c0.x + x0.y*c0.y + x0.z*c0.z + x0.w*c0.w;
        a1 += x1.x*c1.x + x1.y*c1.y + x1.z*c1.z + x1.w*c1.w;
        a2 += x2.x*c2.x + x2.y*c2.y + x2.z*c2.z + x2.w*c2.w;
        a3 += x3.x*c3.x + x3.y*c3.y + x3.z*c3.z + x3.w*c3.w;
    }
    return (a0 + a1) + (a2 + a3);
}

static __device__ __forceinline__ void top2_16(
    const f32x16& a, float* b1r, float* b2r, unsigned pk)
{
#pragma unroll
    for (int r = 0; r < 16; ++r) {
        float p = __uint_as_float((__float_as_uint(a[r]) & 0xFFFFFF80u) | pk);
        b2r[r] = __builtin_amdgcn_fmed3f(p, b1r[r], b2r[r]);
        b1r[r] = fmaxf(p, b1r[r]);
    }
}

// ---- stage 1: grid 512 = 64 token-blocks(256 tok) x 8 splits ----
// Block: 256 threads = 4 waves; wave w covers tokens t0+w*64..+63 as TWO
// 32-row tiles. Per col-tile (32 codes): 8 B-fragments, 16 MFMA 32x32x16
// (2 rt x 8 K-steps), 96-op screen. No LDS, no barriers.
__global__ __launch_bounds__(256)
__attribute__((amdgpu_waves_per_eu(2, 2)))
void lfq_stage1(
    const float* __restrict__ xf, const unsigned short* __restrict__ cbs,
    float* __restrict__ sb1, float* __restrict__ sb2,
    int* __restrict__ si1, int* __restrict__ si2)
{
    const int split = blockIdx.x & 7;
    const int tb    = blockIdx.x >> 3;
    const int t0    = tb * 256;
    const int tid   = threadIdx.x;
    const int w     = tid >> 6;       // wave id = 64-token group
    const int lane  = tid & 63;
    const int col   = lane & 31;      // token-row in tile / code-col
    const int half  = lane >> 5;      // K-half

    // A fragments: ah[rt][m] = x[t0+w*64+rt*32+col][m*16+half*8 .. +8]
    bf16x8 ah[2][8];
#pragma unroll
    for (int rt = 0; rt < 2; ++rt) {
        const float* xr = xf + (size_t)(t0 + w * 64 + rt * 32 + col) * ND + half * 8;
#pragma unroll
        for (int m = 0; m < 8; ++m) {
            float4 v0 = *(const float4*)(xr + m * 16);
            float4 v1 = *(const float4*)(xr + m * 16 + 4);
            u16x8 hu;
            hu[0] = f2bf(v0.x);
            hu[1] = f2bf(v0.y);
            hu[2] = f2bf(v0.z);
            hu[3] = f2bf(v0.w);
            hu[4] = f2bf(v1.x);
            hu[5] = f2bf(v1.y);
            hu[6] = f2bf(v1.z);
            hu[7] = f2bf(v1.w);
            ah[rt][m] = u2b(hu);
        }
    }

    float b1[2][16], b2[2][16];
#pragma unroll
    for (int rt = 0; rt < 2; ++rt)
#pragma unroll
        for (int r = 0; r < 16; ++r) { b1[rt][r] = -3.0e38f; b2[rt][r] = -3.0e38f; }

    // per-lane fragment base: lane l reads byte l*16 of each 1KB fragment
    const unsigned char* gp =
        (const unsigned char*)cbs + (size_t)split * 524288u +
        (unsigned)lane * 16u;

    const f32x16 zq16 = {0.f,0.f,0.f,0.f,0.f,0.f,0.f,0.f,
                         0.f,0.f,0.f,0.f,0.f,0.f,0.f,0.f};

#define LOADB(Q, G)                                                            \
    Q##0 = *(const bf16x8*)((G));                                              \
    Q##1 = *(const bf16x8*)((G) + 1024);                                       \
    Q##2 = *(const bf16x8*)((G) + 2048);                                       \
    Q##3 = *(const bf16x8*)((G) + 3072);                                       \
    Q##4 = *(const bf16x8*)((G) + 4096);                                       \
    Q##5 = *(const bf16x8*)((G) + 5120);                                       \
    Q##6 = *(const bf16x8*)((G) + 6144);                                       \
    Q##7 = *(const bf16x8*)((G) + 7168);

    // col-tile CT: 16 MFMAs over 2 independent chains, then screen
#define CTBODY(Q, CT)                                                          \
    {                                                                          \
        f32x16 a0, a1;                                                         \
        a0 = MF32(ah[0][0], Q##0, zq16, 0,0,0);                                \
        a1 = MF32(ah[1][0], Q##0, zq16, 0,0,0);                                \
        a0 = MF32(ah[0][1], Q##1, a0,   0,0,0);                                \
        a1 = MF32(ah[1][1], Q##1, a1,   0,0,0);                                \
        a0 = MF32(ah[0][2], Q##2, a0,   0,0,0);                                \
        a1 = MF32(ah[1][2], Q##2, a1,   0,0,0);                                \
        a0 = MF32(ah[0][3], Q##3, a0,   0,0,0);                                \
        a1 = MF32(ah[1][3], Q##3, a1,   0,0,0);                                \
        a0 = MF32(ah[0][4], Q##4, a0,   0,0,0);                                \
        a1 = MF32(ah[1][4], Q##4, a1,   0,0,0);                                \
        a0 = MF32(ah[0][5], Q##5, a0,   0,0,0);                                \
        a1 = MF32(ah[1][5], Q##5, a1,   0,0,0);                                \
        a0 = MF32(ah[0][6], Q##6, a0,   0,0,0);                                \
        a1 = MF32(ah[1][6], Q##6, a1,   0,0,0);                                \
        a0 = MF32(ah[0][7], Q##7, a0,   0,0,0);                                \
        a1 = MF32(ah[1][7], Q##7, a1,   0,0,0);                                \
        const unsigned pk = (unsigned)(127 - (CT));                            \
        top2_16(a0, b1[0], b2[0], pk);                                         \
        top2_16(a1, b1[1], b2[1], pk);                                         \
    }

    bf16x8 qa0, qa1, qa2, qa3, qa4, qa5, qa6, qa7;
    bf16x8 qb0, qb1, qb2, qb3, qb4, qb5, qb6, qb7;

    LOADB(qa, gp)                       // col-tile 0

    // 64 col-tiles; unroll 2 (named double buffer, rule #20)
    for (int ct = 0; ct < 62; ct += 2) {
        LOADB(qb, gp + (ct + 1) * 8192)
        CTBODY(qa, ct)
        LOADB(qa, gp + (ct + 2) * 8192)
        CTBODY(qb, ct + 1)
    }
    LOADB(qb, gp + 63 * 8192)
    CTBODY(qa, 62)
    CTBODY(qb, 63)

#undef LOADB
#undef CTBODY

    // unpack (score, code); per-lane code = cb_base + ct*32 + col
    const int cb_base = split * (NC / NSPLIT);
    float v1[2][16], v2[2][16];
    int   c1[2][16], c2[2][16];
#pragma unroll
    for (int rt = 0; rt < 2; ++rt)
#pragma unroll
        for (int r = 0; r < 16; ++r) {
            int j1 = 127 - (int)(__float_as_uint(b1[rt][r]) & 127u);
            int j2 = 127 - (int)(__float_as_uint(b2[rt][r]) & 127u);
            v1[rt][r] = b1[rt][r]; c1[rt][r] = cb_base + j1 * 32 + col;
            v2[rt][r] = b2[rt][r]; c2[rt][r] = cb_base + j2 * 32 + col;
        }

    // cross-lane top-2 merge over the 32 code-lanes of this half
    // (shfl_xor off<32 preserves bit5 -> stays within the half)
#pragma unroll
    for (int rt = 0; rt < 2; ++rt)
#pragma unroll
        for (int r = 0; r < 16; ++r) {
#pragma unroll
            for (int off = 1; off < 32; off <<= 1) {
                float ob1 = __shfl_xor(v1[rt][r], off, 64);
                int   oi1 = __shfl_xor(c1[rt][r], off, 64);
                float ob2 = __shfl_xor(v2[rt][r], off, 64);
                int   oi2 = __shfl_xor(c2[rt][r], off, 64);
                bool gt = (ob1 > v1[rt][r]) ||
                          (ob1 == v1[rt][r] && oi1 < c1[rt][r]);
                float ls = gt ? v1[rt][r] : ob1;
                int   li = gt ? c1[rt][r] : oi1;
                float ws_ = gt ? ob2 : v2[rt][r];
                int   wi = gt ? oi2 : c2[rt][r];
                bool s2 = (ls > ws_) || (ls == ws_ && li < wi);
                v2[rt][r] = s2 ? ls : ws_;
                c2[rt][r] = s2 ? li : wi;
                v1[rt][r] = gt ? ob1 : v1[rt][r];
                c1[rt][r] = gt ? oi1 : c1[rt][r];
            }
        }

    // lane col==0 of each half stores its 16 rows per row-tile
    // (row = (r&3) + 8*(r>>2) + 4*half  [m74/m101-verified C/D layout])
    if (col == 0) {
#pragma unroll
        for (int rt = 0; rt < 2; ++rt)
#pragma unroll
            for (int r = 0; r < 16; ++r) {
                const int row   = (r & 3) + 8 * (r >> 2) + 4 * half;
                const int token = t0 + w * 64 + rt * 32 + row;
                const size_t o  = (size_t)split * NT + token;
                sb1[o] = v1[rt][r]; si1[o] = c1[rt][r];
                sb2[o] = v2[rt][r]; si2[o] = c2[rt][r];
            }
    }
}

// ---- combine: wave-cooperative merge + distributed exact rescore ----
__global__ __launch_bounds__(256) void lfq_combine(
    const float* __restrict__ sb1, const float* __restrict__ sb2,
    const int* __restrict__ si1, const int* __restrict__ si2,
    const float* __restrict__ xf, const float* __restrict__ cf,
    float* __restrict__ out, int out_size)
{
    const int lane = threadIdx.x & 63;
    const int wv   = threadIdx.x >> 6;
    const int g    = lane >> 3;        // token sub-index within wave, 0..7
    const int cl   = lane & 7;         // split index, 0..7
    const int t    = (blockIdx.x * 4 + wv) * 8 + g;

    const size_t o = (size_t)cl * NT + t;
    const float va = sb1[o]; const int ia = si1[o];
    const float vb = sb2[o]; const int ib = si2[o];

    // lane-local best (lowest-id tiebreak), then 8-lane group max
    bool lgt = (vb > va) || (vb == va && ib < ia);
    float m  = lgt ? vb : va;
    int   mi = lgt ? ib : ia;
#pragma unroll
    for (int off = 1; off < 8; off <<= 1) {
        float om = __shfl_xor(m, off, 64);
        int   oi = __shfl_xor(mi, off, 64);
        if (om > m || (om == m && oi < mi)) { m = om; mi = oi; }
    }
    const float A1 = m;
    const int   I1 = mi;

    const bool ba = (va >= A1 - MARGIN);
    const bool bb_ = (vb >= A1 - MARGIN);
    int cnt = (ba ? 1 : 0) + (bb_ ? 1 : 0);
#pragma unroll
    for (int off = 1; off < 8; off <<= 1)
        cnt += __shfl_xor(cnt, off, 64);

    int bi = I1;
    if (cnt > 1) {
        float sa = -__builtin_inff(), sb_ = -__builtin_inff();
        if (ba)  sa  = exact_dot_g(xf, cf, t, ia);
        if (bb_) sb_ = exact_dot_g(xf, cf, t, ib);
        bool g2 = (sb_ > sa) || (sb_ == sa && ib < ia);
        float bs = g2 ? sb_ : sa;
        int  bid = g2 ? ib : ia;
#pragma unroll
        for (int off = 1; off < 8; off <<= 1) {
            float os = __shfl_xor(bs, off, 64);
            int   oi = __shfl_xor(bid, off, 64);
            if (os > bs || (os == bs && oi < bid)) { bs = os; bid = oi; }
        }
        bi = bid;
    }
    if (cl == 0) out[t] = (float)bi;
    if (blockIdx.x == 0 && threadIdx.x == 0 && out_size > NT) out[NT] = 0.0f;
}

// ------------- fallback: round-3 exact fp32 kernel (tiny ws) -------------
__global__ __launch_bounds__(512) void lfq_fp32_argmax(
    const float* __restrict__ xf, const float* __restrict__ cf,
    float* __restrict__ out, int out_size)
{
    const int tid = threadIdx.x;
    const int w   = tid >> 6;
    const int tok = tid & 63;
    const int t0  = blockIdx.x * 64;
    __shared__ float s_sc[8][64];
    __shared__ int   s_ix[8][64];

    float4 xr[32];
    const float4* xrow = (const float4*)(xf + (size_t)(t0 + tok) * ND);
#pragma unroll
    for (int i = 0; i < 32; ++i) xr[i] = xrow[i];

    float bs = -__builtin_inff();
    int   bi = 0;
    const int c_begin = w * (NC / 8);
    for (int c = c_begin; c < c_begin + NC / 8; ++c) {
        float s = exact_dot(xr, cf, c);
        if (s > bs) { bs = s; bi = c; }
    }
    s_sc[w][tok] = bs; s_ix[w][tok] = bi;
    __syncthreads();
    if (tid < 64) {
        float bsf = s_sc[0][tid]; int bif = s_ix[0][tid];
#pragma unroll
        for (int ww = 1; ww < 8; ++ww) {
            float s2 = s_sc[ww][tid]; int ii = s_ix[ww][tid];
            if (s2 > bsf || (s2 == bsf && ii < bif)) { bsf = s2; bif = ii; }
        }
        out[t0 + tid] = (float)bif;
    }
    if (blockIdx.x == 0 && tid == 0 && out_size > NT) out[NT] = 0.0f;
}

extern "C" void kernel_launch(void* const* d_in, const int* in_sizes, int n_in,
                              void* d_out, int out_size, void* d_ws, size_t ws_size,
                              hipStream_t stream) {
    const float* x  = (const float*)d_in[0];
    const float* cb = (const float*)d_in[1];
    float* out = (float*)d_out;

    // ws: cbs 4.19MB (fragment-coalesced image) | sb1/sb2/si1/si2 512KB ea
    const size_t NCE = (size_t)NC * ND;          // 2,097,152 codebook elements
    const size_t NEED = NCE * 2 + (size_t)NT * NSPLIT * 4 * 4;
    if (ws_size >= NEED) {
        char* ws = (char*)d_ws;
        unsigned short* cbs = (unsigned short*)ws;
        char* sp = ws + NCE * 2;
        float* sb1 = (float*)sp;
        float* sb2 = (float*)(sp + (size_t)NT * NSPLIT * 4);
        int*   si1 = (int*)  (sp + (size_t)NT * NSPLIT * 8);
        int*   si2 = (int*)  (sp + (size_t)NT * NSPLIT * 12);

        lfq_convert_cb<<<dim3(1024), dim3(256), 0, stream>>>(
            (const float4*)cb, cbs);
        lfq_stage1<<<dim3((NT / 256) * NSPLIT), dim3(256), 0, stream>>>(
            x, cbs, sb1, sb2, si1, si2);
        lfq_combine<<<dim3(NT / 32), dim3(256), 0, stream>>>(
            sb1, sb2, si1, si2, x, cb, out, out_size);
    } else {
        lfq_fp32_argmax<<<dim3(NT / 64), dim3(512), 0, stream>>>(x, cb, out, out_size);
    }
}

// Round 14
// 155.178 us; speedup vs baseline: 1.1645x; 1.1645x over previous
//
#include <hip/hip_runtime.h>
#include <hip/hip_bf16.h>

// LFQ argmax, round 28: inline-asm pinned load pipeline (counted vmcnt).
// r27: 32x32 shape spilled (VGPR capped 128, WRITE 2KB->11MB) -> void.
// Fresh-eyes datum from the CLEAN rounds: r22/r23 VGPR_Count=100 while
// source-level live state (qa+qb 64 + ah 64 + acc 32 + b1/b2 32) ~ 200.
// The compiler never materialized the double buffer -- it SANK the
// fragment loads to just-before-use to shrink live ranges. So the
// "1-pair-ahead prefetch" assumed in every ledger since r22 never existed
// in the binary; per-pair L2/L3 latency (~200-600cyc; FETCH shows 8.5%
// L2-miss on cbs) is exposed every pair = the ~900cyc/pair idle that no
// source-level scheduling change could touch (compiler re-sank each time).
// Change: 8 fragment loads per pair = ONE asm volatile block of 8x
// global_load_dwordx4 (issue point + dest regs pinned); loop waits with
// counted "s_waitcnt vmcnt(8)" + sched_barrier(0) (rule #18); issue(t+2)
// right after compute(t) frees its set; vmcnt(0) only at tail; vmcnt(0)
// drain after A-prologue. Numerics/screen/merge/combine byte-identical to
// r22. Dropped dead slot-sleep/setprio.
// Validity signal: VGPR_Count ~200-230 (if ~100, pinning failed).
// Canaries: FETCH ~35MB, WRITE ~2MB (spill!), absmax=0.
#define NT 16384
#define ND 128
#define NC 16384
#define NSPLIT 8
#define MARGIN 0.4f       // >= 3x worst pairwise 1-term bf16 comparison error

typedef __bf16 bf16x8 __attribute__((ext_vector_type(8)));
typedef unsigned short u16x8 __attribute__((ext_vector_type(8)));
typedef int i32x4 __attribute__((ext_vector_type(4)));
typedef float f32x4 __attribute__((ext_vector_type(4)));

#define MF __builtin_amdgcn_mfma_f32_16x16x32_bf16
#define B8(Q) __builtin_bit_cast(bf16x8, Q)

static __device__ __forceinline__ unsigned short f2bf(float f) {
    unsigned u = __float_as_uint(f);
    return (unsigned short)((u + 0x7FFFu + ((u >> 16) & 1u)) >> 16);
}
static __device__ __forceinline__ bf16x8 u2b(u16x8 u) {
    return __builtin_bit_cast(bf16x8, u);
}

// ---- codebook fp32 -> bf16 hi, fragment-coalesced image (r22 layout) ----
__global__ __launch_bounds__(256) void lfq_convert_cb(
    const float4* __restrict__ cb4, unsigned short* __restrict__ cbs)
{
    const unsigned i = blockIdx.x * 256 + threadIdx.x;   // 0..262143
    const unsigned c  = i >> 4;          // code 0..16383
    const unsigned k8 = i & 15u;         // dim chunk (d0 = k8*8)
    const float4 v0 = cb4[i * 2];
    const float4 v1 = cb4[i * 2 + 1];
    const unsigned split = c >> 11;
    const unsigned cl    = c & 2047u;
    const unsigned pair  = cl >> 5;
    const unsigned sp    = (cl >> 4) & 1u;
    const unsigned n     = cl & 15u;
    const unsigned k     = k8 >> 2;
    const unsigned quad  = k8 & 3u;
    const unsigned idx = split * 262144u + pair * 4096u + sp * 2048u +
                         k * 512u + quad * 128u + n * 8u;
    u16x8 h;
    h[0] = f2bf(v0.x); h[1] = f2bf(v0.y); h[2] = f2bf(v0.z); h[3] = f2bf(v0.w);
    h[4] = f2bf(v1.x); h[5] = f2bf(v1.y); h[6] = f2bf(v1.z); h[7] = f2bf(v1.w);
    *(u16x8*)(cbs + idx) = h;
}

// exact fp32 dot, register-preloaded x (fallback kernel)
static __device__ __forceinline__ float exact_dot(
    const float4* __restrict__ xr4, const float* __restrict__ cf, int cidx)
{
    const float4* cr = (const float4*)(cf + (size_t)cidx * ND);
    float a0 = 0.f, a1 = 0.f, a2 = 0.f, a3 = 0.f;
#pragma unroll
    for (int i = 0; i < 32; i += 4) {
        float4 x0 = xr4[i+0], x1 = xr4[i+1], x2 = xr4[i+2], x3 = xr4[i+3];
        float4 c0 = cr[i+0],  c1 = cr[i+1],  c2 = cr[i+2],  c3 = cr[i+3];
        a0 += x0.x*c0.x + x0.y*c0.y + x0.z*c0.z + x0.w*c0.w;
        a1 += x1.x*c1.x + x1.y*c1.y + x1.z*c1.z + x1.w*c1.w;
        a2 += x2.x*c2.x + x2.y*c2.y + x2.z*c2.z + x2.w*c2.w;
        a3 += x3.x*c3.x + x3.y*c3.y + x3.z*c3.z + x3.w*c3.w;
    }
    return (a0 + a1) + (a2 + a3);
}

// exact fp32 dot, both operands from global (combine kernel)
static __device__ __forceinline__ float exact_dot_g(
    const float* __restrict__ xf, const float* __restrict__ cf,
    int token, int cidx)
{
    const float4* xr = (const float4*)(xf + (size_t)token * ND);
    const float4* cr = (const float4*)(cf + (size_t)cidx * ND);
    float a0 = 0.f, a1 = 0.f, a2 = 0.f, a3 = 0.f;
#pragma unroll
    for (int i = 0; i < 32; i += 4) {
        float4 x0 = xr[i+0], x1 = xr[i+1], x2 = xr[i+2], x3 = xr[i+3];
        float4 c0 = cr[i+0], c1 = cr[i+1], c2 = cr[i+2], c3 = cr[i+3];
        a0 += x0.x*c0.x + x0.y*c0.y + x0.z*c0.z + x0.w*c0.w;
        a1 += x1.x*c1.x + x1.y*c1.y + x1.z*c1.z + x1.w*c1.w;
        a2 += x2.x*c2.x + x2.y*c2.y + x2.z*c2.z + x2.w*c2.w;
        a3 += x3.x*c3.x + x3.y*c3.y + x3.z*c3.z + x3.w*c3.w;
    }
    return (a0 + a1) + (a2 + a3);
}

static __device__ __forceinline__ void top2_upd(
    const f32x4& a, float* b1r, float* b2r, unsigned pk)
{
#pragma unroll
    for (int r4 = 0; r4 < 4; ++r4) {
        float p = __uint_as_float((__float_as_uint(a[r4]) & 0xFFFFFF80u) | pk);
        b2r[r4] = __builtin_amdgcn_fmed3f(p, b1r[r4], b2r[r4]);
        b1r[r4] = fmaxf(p, b1r[r4]);
    }
}

// ---- stage 1: grid 512 = 64 token-blocks(256 tok) x 8 splits ----
// Block: 256 threads = 4 waves; wave w covers tokens t0+w*64..+63 (tt=4).
// B fragments: asm-pinned global loads, counted-vmcnt pipeline, no LDS,
// no barriers.
__global__ __launch_bounds__(256)
__attribute__((amdgpu_waves_per_eu(2, 2)))
void lfq_stage1(
    const float* __restrict__ xf, const unsigned short* __restrict__ cbs,
    float* __restrict__ sb1, float* __restrict__ sb2,
    int* __restrict__ si1, int* __restrict__ si2)
{
    const int split = blockIdx.x & 7;
    const int tb    = blockIdx.x >> 3;
    const int t0    = tb * 256;
    const int tid   = threadIdx.x;
    const int w     = tid >> 6;       // wave id = token-group, 0..3
    const int lane  = tid & 63;
    const int n     = lane & 15;
    const int quad  = lane >> 4;

    // A fragments: tokens t0 + w*64 + tt*16 + n, tt=0..3; fp32 -> bf16 (RN).
    bf16x8 ah[4][4];
#pragma unroll
    for (int tt = 0; tt < 4; ++tt) {
        const float* xr = xf + (size_t)(t0 + w * 64 + tt * 16 + n) * ND + quad * 8;
#pragma unroll
        for (int kk = 0; kk < 4; ++kk) {
            float4 v0 = *(const float4*)(xr + kk * 32);
            float4 v1 = *(const float4*)(xr + kk * 32 + 4);
            u16x8 hu;
            hu[0] = f2bf(v0.x);
            hu[1] = f2bf(v0.y);
            hu[2] = f2bf(v0.z);
            hu[3] = f2bf(v0.w);
            hu[4] = f2bf(v1.x);
            hu[5] = f2bf(v1.y);
            hu[6] = f2bf(v1.z);
            hu[7] = f2bf(v1.w);
            ah[tt][kk] = u2b(hu);
        }
    }

    float b1[4][4], b2[4][4];
#pragma unroll
    for (int tt = 0; tt < 4; ++tt)
#pragma unroll
        for (int r = 0; r < 4; ++r) { b1[tt][r] = -3.0e38f; b2[tt][r] = -3.0e38f; }

    // per-lane fragment base: lane l reads byte l*16 of each 1KB block
    const unsigned char* gp =
        (const unsigned char*)cbs + (size_t)split * 524288u +
        (unsigned)lane * 16u;

    const f32x4 zq = {0.f, 0.f, 0.f, 0.f};

    // Issue the 8 fragment loads of one pair; issue point and dest regs are
    // PINNED (compiler cannot sink/split). Offsets 0..3072 within two 4KB
    // halves keep the 13-bit signed imm in range.
#define ISSUE(Q, G)                                                            \
    asm volatile(                                                              \
        "global_load_dwordx4 %0, %8, off\n\t"                                  \
        "global_load_dwordx4 %1, %8, off offset:1024\n\t"                      \
        "global_load_dwordx4 %2, %8, off offset:2048\n\t"                      \
        "global_load_dwordx4 %3, %8, off offset:3072\n\t"                      \
        "global_load_dwordx4 %4, %9, off\n\t"                                  \
        "global_load_dwordx4 %5, %9, off offset:1024\n\t"                      \
        "global_load_dwordx4 %6, %9, off offset:2048\n\t"                      \
        "global_load_dwordx4 %7, %9, off offset:3072"                          \
        : "=&v"(Q##0), "=&v"(Q##1), "=&v"(Q##2), "=&v"(Q##3),                  \
          "=&v"(Q##4), "=&v"(Q##5), "=&v"(Q##6), "=&v"(Q##7)                   \
        : "v"((const void*)(G)), "v"((const void*)((G) + 4096)));

    // Counted wait: pair t retired, pair t+1 (8 loads) still in flight.
    // sched_barrier(0) blocks MFMA hoisting past the asm waitcnt (rule #18).
#define WAITV8                                                                 \
    asm volatile("s_waitcnt vmcnt(8)" ::: "memory");                           \
    __builtin_amdgcn_sched_barrier(0);
#define WAITV0                                                                 \
    asm volatile("s_waitcnt vmcnt(0)" ::: "memory");                           \
    __builtin_amdgcn_sched_barrier(0);

    // compute pair p: 32 MFMAs over 8 chains, then 8 top-2 screens
#define COMPUTE(Q, P)                                                          \
    {                                                                          \
        f32x4 aA0, aA1, aA2, aA3, aB0, aB1, aB2, aB3;                          \
        aA0 = MF(ah[0][0], B8(Q##0), zq,  0,0,0);                              \
        aA1 = MF(ah[1][0], B8(Q##0), zq,  0,0,0);                              \
        aA2 = MF(ah[2][0], B8(Q##0), zq,  0,0,0);                              \
        aA3 = MF(ah[3][0], B8(Q##0), zq,  0,0,0);                              \
        aB0 = MF(ah[0][0], B8(Q##4), zq,  0,0,0);                              \
        aB1 = MF(ah[1][0], B8(Q##4), zq,  0,0,0);                              \
        aB2 = MF(ah[2][0], B8(Q##4), zq,  0,0,0);                              \
        aB3 = MF(ah[3][0], B8(Q##4), zq,  0,0,0);                              \
        aA0 = MF(ah[0][1], B8(Q##1), aA0, 0,0,0);                              \
        aA1 = MF(ah[1][1], B8(Q##1), aA1, 0,0,0);                              \
        aA2 = MF(ah[2][1], B8(Q##1), aA2, 0,0,0);                              \
        aA3 = MF(ah[3][1], B8(Q##1), aA3, 0,0,0);                              \
        aB0 = MF(ah[0][1], B8(Q##5), aB0, 0,0,0);                              \
        aB1 = MF(ah[1][1], B8(Q##5), aB1, 0,0,0);                              \
        aB2 = MF(ah[2][1], B8(Q##5), aB2, 0,0,0);                              \
        aB3 = MF(ah[3][1], B8(Q##5), aB3, 0,0,0);                              \
        aA0 = MF(ah[0][2], B8(Q##2), aA0, 0,0,0);                              \
        aA1 = MF(ah[1][2], B8(Q##2), aA1, 0,0,0);                              \
        aA2 = MF(ah[2][2], B8(Q##2), aA2, 0,0,0);                              \
        aA3 = MF(ah[3][2], B8(Q##2), aA3, 0,0,0);                              \
        aB0 = MF(ah[0][2], B8(Q##6), aB0, 0,0,0);                              \
        aB1 = MF(ah[1][2], B8(Q##6), aB1, 0,0,0);                              \
        aB2 = MF(ah[2][2], B8(Q##6), aB2, 0,0,0);                              \
        aB3 = MF(ah[3][2], B8(Q##6), aB3, 0,0,0);                              \
        aA0 = MF(ah[0][3], B8(Q##3), aA0, 0,0,0);                              \
        aA1 = MF(ah[1][3], B8(Q##3), aA1, 0,0,0);                              \
        aA2 = MF(ah[2][3], B8(Q##3), aA2, 0,0,0);                              \
        aA3 = MF(ah[3][3], B8(Q##3), aA3, 0,0,0);                              \
        aB0 = MF(ah[0][3], B8(Q##7), aB0, 0,0,0);                              \
        aB1 = MF(ah[1][3], B8(Q##7), aB1, 0,0,0);                              \
        aB2 = MF(ah[2][3], B8(Q##7), aB2, 0,0,0);                              \
        aB3 = MF(ah[3][3], B8(Q##7), aB3, 0,0,0);                              \
        const unsigned pkA = (unsigned)(127 - (P) * 2);                        \
        const unsigned pkB = (unsigned)(127 - (P) * 2 - 1);                    \
        top2_upd(aA0, b1[0], b2[0], pkA);                                      \
        top2_upd(aA1, b1[1], b2[1], pkA);                                      \
        top2_upd(aA2, b1[2], b2[2], pkA);                                      \
        top2_upd(aA3, b1[3], b2[3], pkA);                                      \
        top2_upd(aB0, b1[0], b2[0], pkB);                                      \
        top2_upd(aB1, b1[1], b2[1], pkB);                                      \
        top2_upd(aB2, b1[2], b2[2], pkB);                                      \
        top2_upd(aB3, b1[3], b2[3], pkB);                                      \
    }

    i32x4 qa0, qa1, qa2, qa3, qa4, qa5, qa6, qa7;
    i32x4 qb0, qb1, qb2, qb3, qb4, qb5, qb6, qb7;

    WAITV0                               // drain A-prologue loads
    ISSUE(qa, gp)                        // pair 0
    ISSUE(qb, gp + 8192)                 // pair 1

    for (int p = 0; p < 62; p += 2) {
        WAITV8                           // pair p landed; p+1 in flight
        COMPUTE(qa, p)
        ISSUE(qa, gp + (p + 2) * 8192)   // into the set compute(p) freed
        WAITV8                           // pair p+1 landed; p+2 in flight
        COMPUTE(qb, p + 1)
        ISSUE(qb, gp + (p + 3) * 8192)
    }
    WAITV8                               // pair 62 landed; 63 in flight
    COMPUTE(qa, 62)
    WAITV0                               // pair 63 landed
    COMPUTE(qb, 63)

#undef ISSUE
#undef WAITV8
#undef WAITV0
#undef COMPUTE

    // unpack (score, code) and cross-lane top-2 merge over 16 code-lanes
    const int cb_base = split * (NC / NSPLIT);
    float v1[4][4], v2[4][4];
    int   c1[4][4], c2[4][4];
#pragma unroll
    for (int tt = 0; tt < 4; ++tt)
#pragma unroll
        for (int r = 0; r < 4; ++r) {
            int j1 = 127 - (int)(__float_as_uint(b1[tt][r]) & 127u);
            int j2 = 127 - (int)(__float_as_uint(b2[tt][r]) & 127u);
            v1[tt][r] = b1[tt][r]; c1[tt][r] = cb_base + j1 * 16 + n;
            v2[tt][r] = b2[tt][r]; c2[tt][r] = cb_base + j2 * 16 + n;
        }

#pragma unroll
    for (int tt = 0; tt < 4; ++tt)
#pragma unroll
        for (int r = 0; r < 4; ++r) {
#pragma unroll
            for (int off = 1; off < 16; off <<= 1) {
                float ob1 = __shfl_xor(v1[tt][r], off, 64);
                int   oi1 = __shfl_xor(c1[tt][r], off, 64);
                float ob2 = __shfl_xor(v2[tt][r], off, 64);
                int   oi2 = __shfl_xor(c2[tt][r], off, 64);
                bool gt = (ob1 > v1[tt][r]) ||
                          (ob1 == v1[tt][r] && oi1 < c1[tt][r]);
                float ls = gt ? v1[tt][r] : ob1;
                int   li = gt ? c1[tt][r] : oi1;
                float ws_ = gt ? ob2 : v2[tt][r];
                int   wi = gt ? oi2 : c2[tt][r];
                bool s2 = (ls > ws_) || (ls == ws_ && li < wi);
                v2[tt][r] = s2 ? ls : ws_;
                c2[tt][r] = s2 ? li : wi;
                v1[tt][r] = gt ? ob1 : v1[tt][r];
                c1[tt][r] = gt ? oi1 : c1[tt][r];
            }
        }

    // each wave owns its 64 tokens exclusively -> direct store
    if (n == 0) {
#pragma unroll
        for (int tt = 0; tt < 4; ++tt)
#pragma unroll
            for (int r = 0; r < 4; ++r) {
                const int token = t0 + w * 64 + tt * 16 + quad * 4 + r;
                const size_t o = (size_t)split * NT + token;
                sb1[o] = v1[tt][r]; si1[o] = c1[tt][r];
                sb2[o] = v2[tt][r]; si2[o] = c2[tt][r];
            }
    }
}

// ---- combine: wave-cooperative merge + distributed exact rescore ----
__global__ __launch_bounds__(256) void lfq_combine(
    const float* __restrict__ sb1, const float* __restrict__ sb2,
    const int* __restrict__ si1, const int* __restrict__ si2,
    const float* __restrict__ xf, const float* __restrict__ cf,
    float* __restrict__ out, int out_size)
{
    const int lane = threadIdx.x & 63;
    const int wv   = threadIdx.x >> 6;
    const int g    = lane >> 3;        // token sub-index within wave, 0..7
    const int cl   = lane & 7;         // split index, 0..7
    const int t    = (blockIdx.x * 4 + wv) * 8 + g;

    const size_t o = (size_t)cl * NT + t;
    const float va = sb1[o]; const int ia = si1[o];
    const float vb = sb2[o]; const int ib = si2[o];

    // lane-local best (lowest-id tiebreak), then 8-lane group max
    bool lgt = (vb > va) || (vb == va && ib < ia);
    float m  = lgt ? vb : va;
    int   mi = lgt ? ib : ia;
#pragma unroll
    for (int off = 1; off < 8; off <<= 1) {
        float om = __shfl_xor(m, off, 64);
        int   oi = __shfl_xor(mi, off, 64);
        if (om > m || (om == m && oi < mi)) { m = om; mi = oi; }
    }
    const float A1 = m;
    const int   I1 = mi;

    const bool ba = (va >= A1 - MARGIN);
    const bool bb_ = (vb >= A1 - MARGIN);
    int cnt = (ba ? 1 : 0) + (bb_ ? 1 : 0);
#pragma unroll
    for (int off = 1; off < 8; off <<= 1)
        cnt += __shfl_xor(cnt, off, 64);

    int bi = I1;
    if (cnt > 1) {
        float sa = -__builtin_inff(), sb_ = -__builtin_inff();
        if (ba)  sa  = exact_dot_g(xf, cf, t, ia);
        if (bb_) sb_ = exact_dot_g(xf, cf, t, ib);
        bool g2 = (sb_ > sa) || (sb_ == sa && ib < ia);
        float bs = g2 ? sb_ : sa;
        int  bid = g2 ? ib : ia;
#pragma unroll
        for (int off = 1; off < 8; off <<= 1) {
            float os = __shfl_xor(bs, off, 64);
            int   oi = __shfl_xor(bid, off, 64);
            if (os > bs || (os == bs && oi < bid)) { bs = os; bid = oi; }
        }
        bi = bid;
    }
    if (cl == 0) out[t] = (float)bi;
    if (blockIdx.x == 0 && threadIdx.x == 0 && out_size > NT) out[NT] = 0.0f;
}

// ------------- fallback: round-3 exact fp32 kernel (tiny ws) -------------
__global__ __launch_bounds__(512) void lfq_fp32_argmax(
    const float* __restrict__ xf, const float* __restrict__ cf,
    float* __restrict__ out, int out_size)
{
    const int tid = threadIdx.x;
    const int w   = tid >> 6;
    const int tok = tid & 63;
    const int t0  = blockIdx.x * 64;
    __shared__ float s_sc[8][64];
    __shared__ int   s_ix[8][64];

    float4 xr[32];
    const float4* xrow = (const float4*)(xf + (size_t)(t0 + tok) * ND);
#pragma unroll
    for (int i = 0; i < 32; ++i) xr[i] = xrow[i];

    float bs = -__builtin_inff();
    int   bi = 0;
    const int c_begin = w * (NC / 8);
    for (int c = c_begin; c < c_begin + NC / 8; ++c) {
        float s = exact_dot(xr, cf, c);
        if (s > bs) { bs = s; bi = c; }
    }
    s_sc[w][tok] = bs; s_ix[w][tok] = bi;
    __syncthreads();
    if (tid < 64) {
        float bsf = s_sc[0][tid]; int bif = s_ix[0][tid];
#pragma unroll
        for (int ww = 1; ww < 8; ++ww) {
            float s2 = s_sc[ww][tid]; int ii = s_ix[ww][tid];
            if (s2 > bsf || (s2 == bsf && ii < bif)) { bsf = s2; bif = ii; }
        }
        out[t0 + tid] = (float)bif;
    }
    if (blockIdx.x == 0 && tid == 0 && out_size > NT) out[NT] = 0.0f;
}

extern "C" void kernel_launch(void* const* d_in, const int* in_sizes, int n_in,
                              void* d_out, int out_size, void* d_ws, size_t ws_size,
                              hipStream_t stream) {
    const float* x  = (const float*)d_in[0];
    const float* cb = (const float*)d_in[1];
    float* out = (float*)d_out;

    // ws: cbs 4.19MB (fragment-coalesced image) | sb1/sb2/si1/si2 512KB ea
    const size_t NCE = (size_t)NC * ND;          // 2,097,152 codebook elements
    const size_t NEED = NCE * 2 + (size_t)NT * NSPLIT * 4 * 4;
    if (ws_size >= NEED) {
        char* ws = (char*)d_ws;
        unsigned short* cbs = (unsigned short*)ws;
        char* sp = ws + NCE * 2;
        float* sb1 = (float*)sp;
        float* sb2 = (float*)(sp + (size_t)NT * NSPLIT * 4);
        int*   si1 = (int*)  (sp + (size_t)NT * NSPLIT * 8);
        int*   si2 = (int*)  (sp + (size_t)NT * NSPLIT * 12);

        lfq_convert_cb<<<dim3(1024), dim3(256), 0, stream>>>(
            (const float4*)cb, cbs);
        lfq_stage1<<<dim3((NT / 256) * NSPLIT), dim3(256), 0, stream>>>(
            x, cbs, sb1, sb2, si1, si2);
        lfq_combine<<<dim3(NT / 32), dim3(256), 0, stream>>>(
            sb1, sb2, si1, si2, x, cb, out, out_size);
    } else {
        lfq_fp32_argmax<<<dim3(NT / 64), dim3(512), 0, stream>>>(x, cb, out, out_size);
    }
}